// Round 11
// baseline (197.111 us; speedup 1.0000x reference)
//
#include <hip/hip_runtime.h>
#include <math.h>

#define NN   4096
#define NN4  (NN/4)
#define CAP  128      // slots per row; Poisson(64) -> 128 = 8 sigma, never hit
#define RPB  4        // rows per block in diag3 phase
#define D3B  (NN/RPB) // 1024 blocks: 4/CU needed, 8/CU capacity -> co-resident
#define NGRP 16       // tail groups (blocks 0..15 reduce 256 rows each)
#define GPAD 32       // ints per counter line (128 B)

// ---- workspace layout (bytes from d_ws) ----
// bar  @ 0       : 4*GPAD i32 (512 B)  grid-barrier counters (zeroed by zerobar)
// cnt  @ 512     : NN i32 (16 KB)      scatter slot counters (zeroed in P0)
// entp @ 16896   : NN*CAP u32 (2 MiB)  packed col<<8|w entries (zeroed in P0)
// ND   @ 2114048 : NN u64 (32 KB)      packed float2 {N, D3}
// gsum @ 2146816 : NGRP*4 f64 (512 B)  group OLS partials

// ---------------- bootstrap: zero the grid-barrier words ----------------
// Needed every call: d_ws is poisoned 0xAA once before timing. Everything else
// is zeroed inside the fused kernel (P0) behind barrier 0.
__global__ __launch_bounds__(128) void zerobar_kernel(int* __restrict__ bar) {
    bar[threadIdx.x] = 0;   // 4*GPAD = 128 ints
}

// Relaxed agent-scope counting barrier. Cheap MALL ops only — NO threadfence
// (R4: per-block L2 flush = 425us), no cg::grid.sync (hidden cache maintenance).
// Pre-barrier __syncthreads drains each wave's outstanding stores (compiler
// emits vmcnt(0) before s_barrier), so all block writes are at the MALL before
// the arrival RMW. Requires whole grid co-resident (capacity argument above).
__device__ __forceinline__ void gridbar(int* __restrict__ c, int tid) {
    __syncthreads();
    if (tid == 0) {
        __hip_atomic_fetch_add(c, 1, __ATOMIC_RELAXED, __HIP_MEMORY_SCOPE_AGENT);
        while (__hip_atomic_load(c, __ATOMIC_RELAXED, __HIP_MEMORY_SCOPE_AGENT) < D3B)
            __builtin_amdgcn_s_sleep(2);
    }
    __syncthreads();
}

// ---------------- everything fused: zero -> scatter -> diag3 -> OLS ----------
// Coherence rule: every buffer written by one block and read by another is
// written ONLY via agent-scope write-through stores (or device-scope RMWs),
// so no L2 ever holds a dirty/stale line; entp is first READ in P2, where
// normal loads pull clean lines from MALL and stay L2-cached for reuse.
__global__ __launch_bounds__(256, 4) void fused_kernel(
        const int* __restrict__ idx, const float* __restrict__ wgt, int m,
        const int* __restrict__ lst, int nl,
        int* __restrict__ cnt, unsigned* __restrict__ entp,
        unsigned long long* __restrict__ ND, double* __restrict__ gsum,
        int* __restrict__ bar, float* __restrict__ out) {
    __shared__ float    lrow[NN];       // 16 KB dense image of current row
    __shared__ unsigned witem[2 * CAP]; // entp base index per 64-entry chunk
    __shared__ float    wa[2 * CAP];    // aij per chunk
    __shared__ int      nit;
    __shared__ float    red[8];
    __shared__ double   dsum[4][4];
    __shared__ double   wb[2];
    __shared__ double   sh[4];

    const int tid  = threadIdx.x;
    const int bid  = blockIdx.x;
    const int gtid = bid * 256 + tid;
    const int warp = tid >> 6, lane = tid & 63;

    // ---- P0: zero cnt + entp (agent write-through: MALL truth, no L2 lines) --
    __hip_atomic_store((unsigned long long*)entp + gtid, 0ull,
                       __ATOMIC_RELAXED, __HIP_MEMORY_SCOPE_AGENT);
    if (gtid < NN)
        __hip_atomic_store(cnt + gtid, 0, __ATOMIC_RELAXED, __HIP_MEMORY_SCOPE_AGENT);
    gridbar(bar + 0 * GPAD, tid);

    // ---- P1: scatter edges, symmetrized (s,d)+(d,s), duplicates kept raw ----
    // A = scatter + A^T - diag(diag): row s gets (d,w), row d gets (s,w) once.
    if (gtid < m) {
        int2 sd = ((const int2*)idx)[gtid];
        int s = sd.x, d = sd.y;
        unsigned ival = (unsigned)(int)wgt[gtid];
        if (ival > 255u) ival = 255u;
        int p = atomicAdd(cnt + s, 1);          // device-scope RMW at MALL
        if (p < CAP)
            __hip_atomic_store(entp + (size_t)s * CAP + p, ((unsigned)d << 8) | ival,
                               __ATOMIC_RELAXED, __HIP_MEMORY_SCOPE_AGENT);
        if (s != d) {
            int q = atomicAdd(cnt + d, 1);
            if (q < CAP)
                __hip_atomic_store(entp + (size_t)d * CAP + q, ((unsigned)s << 8) | ival,
                                   __ATOMIC_RELAXED, __HIP_MEMORY_SCOPE_AGENT);
        }
    }
    gridbar(bar + 1 * GPAD, tid);

    // ---- P2: diag(A^3)_i + rowsum, 4 rows per block (R10 interior) ----------
    // diag(A^3)_i = sum_{(j,w) in row i} w * sum_{(k,w') in row j} w' * A_ik;
    // A_ik from dense LDS image (LDS atomicAdd merge; exact int f32 adds ->
    // order-independent). Zero-filled entp: empty slots decode to w=0 -> no
    // masking, fixed 2 chunks per entry.
    {
        const int i0 = bid * RPB;
        float4* l4 = (float4*)lrow;
        unsigned pk = 0u;
        if (tid < CAP) pk = entp[(size_t)i0 * CAP + tid];

        for (int rr = 0; rr < RPB; ++rr) {
            const int i = i0 + rr;
            for (int k = tid; k < NN4; k += 256) l4[k] = make_float4(0.f, 0.f, 0.f, 0.f);
            if (tid == 0) nit = 0;
            __syncthreads();

            float vv = 0.f;
            if (tid < CAP) {
                vv = (float)(pk & 0xffu);
                if (vv > 0.f) {
                    int col = pk >> 8;
                    atomicAdd(&lrow[col], vv);           // LDS merge (exact)
                    int slot = atomicAdd(&nit, 2);
                    unsigned base = (unsigned)col * CAP;
                    witem[slot]     = base;      wa[slot]     = vv;
                    witem[slot + 1] = base + 64; wa[slot + 1] = vv;
                }
            }
            float nsum = vv;
            for (int o = 32; o; o >>= 1) nsum += __shfl_down(nsum, o);
            if (lane == 0) red[warp] = nsum;
            __syncthreads();
            const int NIT = nit;

            unsigned pknext = 0u;
            if (rr + 1 < RPB && tid < CAP) pknext = entp[(size_t)(i + 1) * CAP + tid];
            asm volatile("" : "+v"(pknext));

            float acc = 0.f;
            for (int t = warp; t < NIT; t += 16) {
                const int t1 = t + 4, t2 = t + 8, t3 = t + 12;
                const bool b1 = t1 < NIT, b2 = t2 < NIT, b3 = t3 < NIT;
                unsigned u0 = witem[t];
                unsigned u1 = b1 ? witem[t1] : 0u;
                unsigned u2 = b2 ? witem[t2] : 0u;
                unsigned u3 = b3 ? witem[t3] : 0u;
                float a0 = wa[t];
                float a1 = b1 ? wa[t1] : 0.f;
                float a2 = b2 ? wa[t2] : 0.f;
                float a3 = b3 ? wa[t3] : 0.f;
                unsigned q0 = entp[u0 + lane];   // normal loads: L2-resident reuse
                unsigned q1 = entp[u1 + lane];
                unsigned q2 = entp[u2 + lane];
                unsigned q3 = entp[u3 + lane];
                float d0 = (float)(q0 & 0xffu) * lrow[q0 >> 8];
                float d1 = (float)(q1 & 0xffu) * lrow[q1 >> 8];
                float d2 = (float)(q2 & 0xffu) * lrow[q2 >> 8];
                float d3 = (float)(q3 & 0xffu) * lrow[q3 >> 8];
                acc += a0 * d0 + a1 * d1 + a2 * d2 + a3 * d3;
            }
            for (int o = 32; o; o >>= 1) acc += __shfl_down(acc, o);
            if (lane == 0) red[4 + warp] = acc;
            __syncthreads();

            if (tid == 0) {
                float2 nd = make_float2(red[0] + red[1] + red[2] + red[3],
                                        red[4] + red[5] + red[6] + red[7]);
                unsigned long long bits;
                __builtin_memcpy(&bits, &nd, 8);
                __hip_atomic_store(ND + i, bits, __ATOMIC_RELAXED, __HIP_MEMORY_SCOPE_AGENT);
            }
            pk = pknext;
        }
    }
    gridbar(bar + 2 * GPAD, tid);

    // ---- P3: 16 group finishers, 256 rows each -> fp64 OLS partials ---------
    if (bid < NGRP) {
        int r = bid * 256 + tid;
        unsigned long long bits = __hip_atomic_load(ND + r, __ATOMIC_RELAXED,
                                                    __HIP_MEMORY_SCOPE_AGENT);
        float2 nd; __builtin_memcpy(&nd, &bits, 8);
        double Nd = (double)nd.x;
        double Ed = Nd + 0.5 * (double)nd.y;
        double ln = (double)logf((float)(Nd + 1e-20));
        double le = (double)logf((float)(Ed + 1e-20));
        double p1 = ln, p2 = ln * ln, p3 = le, p4 = ln * le;
        for (int o = 32; o; o >>= 1) {
            p1 += __shfl_down(p1, o);
            p2 += __shfl_down(p2, o);
            p3 += __shfl_down(p3, o);
            p4 += __shfl_down(p4, o);
        }
        if (lane == 0) {
            dsum[warp][0] = p1; dsum[warp][1] = p2;
            dsum[warp][2] = p3; dsum[warp][3] = p4;
        }
        __syncthreads();
        if (tid == 0) {
            for (int k = 0; k < 4; ++k) {
                double v = dsum[0][k] + dsum[1][k] + dsum[2][k] + dsum[3][k];
                __hip_atomic_store(gsum + bid * 4 + k, v, __ATOMIC_RELAXED,
                                   __HIP_MEMORY_SCOPE_AGENT);
            }
        }
    }
    gridbar(bar + 3 * GPAD, tid);

    // ---- P4: block 0 solves 2x2 OLS + 512-target residual -------------------
    if (bid != 0) return;
    if (warp == 0) {
        double s1 = 0, s2 = 0, t0 = 0, t1 = 0;
        if (lane < NGRP) {
            s1 = __hip_atomic_load(gsum + lane * 4 + 0, __ATOMIC_RELAXED, __HIP_MEMORY_SCOPE_AGENT);
            s2 = __hip_atomic_load(gsum + lane * 4 + 1, __ATOMIC_RELAXED, __HIP_MEMORY_SCOPE_AGENT);
            t0 = __hip_atomic_load(gsum + lane * 4 + 2, __ATOMIC_RELAXED, __HIP_MEMORY_SCOPE_AGENT);
            t1 = __hip_atomic_load(gsum + lane * 4 + 3, __ATOMIC_RELAXED, __HIP_MEMORY_SCOPE_AGENT);
        }
        for (int o = 32; o; o >>= 1) {
            s1 += __shfl_down(s1, o);
            s2 += __shfl_down(s2, o);
            t0 += __shfl_down(t0, o);
            t1 += __shfl_down(t1, o);
        }
        if (lane == 0) {
            double n = (double)NN;
            double det = n * s2 - s1 * s1;
            wb[0] = (n * t1 - s1 * t0) / det;   // w
            wb[1] = (s2 * t0 - s1 * t1) / det;  // b
        }
    }
    __syncthreads();
    const double w = wb[0];
    const double eb = exp(wb[1]);
    const float wf = (float)w;
    double racc = 0;
    for (int p = tid; p < nl; p += 256) {
        int r = lst[p];
        unsigned long long bits = __hip_atomic_load(ND + r, __ATOMIC_RELAXED,
                                                    __HIP_MEMORY_SCOPE_AGENT);
        float2 nd; __builtin_memcpy(&nd, &bits, 8);
        double Nd = (double)nd.x;
        double Ed = Nd + 0.5 * (double)nd.y;
        double pr = (nd.x > 0.f) ? (double)exp2f(wf * log2f(nd.x)) : 0.0;
        double rv = eb * pr - Ed;
        racc += rv * rv;
    }
    for (int o = 32; o; o >>= 1) racc += __shfl_down(racc, o);
    if (lane == 0) sh[warp] = racc;
    __syncthreads();
    if (tid == 0) out[0] = (float)(sh[0] + sh[1] + sh[2] + sh[3]);
}

extern "C" void kernel_launch(void* const* d_in, const int* in_sizes, int n_in,
                              void* d_out, int out_size, void* d_ws, size_t ws_size,
                              hipStream_t stream) {
    const int*   tri_idx = (const int*)d_in[0];
    const float* tri_w   = (const float*)d_in[1];
    const int*   lst     = (const int*)d_in[2];
    const int m  = in_sizes[1];          // number of edges
    const int nl = in_sizes[2];          // number of targets

    char* base = (char*)d_ws;
    int*      bar  = (int*)base;                             // 512 B
    int*      cnt  = (int*)(base + 512);                     // 16 KB
    unsigned* entp = (unsigned*)(base + 16896);              // 2 MiB
    unsigned long long* ND = (unsigned long long*)(base + 2114048);  // 32 KB
    double*   gsum = (double*)(base + 2146816);              // 512 B
    float*    out  = (float*)d_out;

    zerobar_kernel<<<1, 128, 0, stream>>>(bar);
    fused_kernel<<<D3B, 256, 0, stream>>>(tri_idx, tri_w, m, lst, nl,
                                          cnt, entp, ND, gsum, bar, out);
}

// Round 12
// 59.250 us; speedup vs baseline: 3.3268x; 3.3268x over previous
//
#include <hip/hip_runtime.h>
#include <math.h>

#define NN   4096
#define NN4  (NN/4)
#define CAP  128      // slots per row; Poisson(64) -> 128 = 8 sigma, never hit
#define RPB  4        // rows per block in diag3 phase
#define D3B  (NN/RPB) // 1024 blocks: 4/CU needed, 8/CU LDS capacity -> co-resident
#define NGRP 16       // barrier/tail groups
#define GPAD 32       // ints per counter line (128 B)

// ---- workspace layout (bytes from d_ws) ----
// ctr  @ 0       : 35*GPAD i32        go | 16 bar-grp | bar-glob | 16 tail-grp | tail-glob
// cnt  @ 4608    : NN i32 (16 KB)     scatter slot counters
// entp @ 20992   : NN*CAP u32 (2 MiB) packed col<<8|w entries
// ND   @ 2118144 : NN u64 (32 KB)     packed float2 {N, D3}
// gsum @ 2150912 : NGRP*4 f64 (512 B) group OLS partials
#define OFF_CNT  4608
#define OFF_ENTP 20992
#define OFF_ND   2118144
#define OFF_GSUM 2150912
#define ZBYTES   OFF_ND            // zero ctr+cnt+entp (ND/gsum fully overwritten)
#define Z4       (ZBYTES / 16)

// counter indices (ints)
#define C_GO    0
#define C_BGRP  (1 * GPAD)         // 16 lines
#define C_BGLOB (17 * GPAD)
#define C_TGRP  (18 * GPAD)        // 16 lines
#define C_TGLOB (34 * GPAD)

// ---------------- bootstrap: zero ctr + cnt + entp ----------------
// Separate dispatch: end-of-kernel writeback + next dispatch's acquire give
// coherence for free. Zero-filled entp is load-bearing (R10): empty slots
// decode to (col 0, w 0) -> contribute exactly 0 -> no masking in inner loop.
__global__ __launch_bounds__(256) void zeroall_kernel(float4* __restrict__ z) {
    int t = blockIdx.x * 256 + threadIdx.x;
    if (t < Z4) z[t] = make_float4(0.f, 0.f, 0.f, 0.f);
}

// Two-level grid barrier with broadcast release.
// R11 lesson: 1024 same-line RMW arrivals + same-line polling = R5's MALL
// serialization (~50us/barrier). Here: arrivals spread over 16 lines (<=64
// serialized RMWs each, parallel across lines), release via ONE go word
// written once and polled read-only (reads don't serialize like RMWs).
__device__ __forceinline__ void gridbar(int* __restrict__ c, int tid, int bid) {
    __syncthreads();   // each wave drains its own stores (vmcnt) before s_barrier
    if (tid == 0) {
        int v = __hip_atomic_fetch_add(c + C_BGRP + (bid & 15) * GPAD, 1,
                                       __ATOMIC_RELAXED, __HIP_MEMORY_SCOPE_AGENT);
        if (v == 63) {
            int vg = __hip_atomic_fetch_add(c + C_BGLOB, 1,
                                            __ATOMIC_RELAXED, __HIP_MEMORY_SCOPE_AGENT);
            if (vg == NGRP - 1)
                __hip_atomic_store(c + C_GO, 1, __ATOMIC_RELAXED, __HIP_MEMORY_SCOPE_AGENT);
        }
        while (__hip_atomic_load(c + C_GO, __ATOMIC_RELAXED, __HIP_MEMORY_SCOPE_AGENT) == 0)
            __builtin_amdgcn_s_sleep(8);
    }
    __syncthreads();
}

// ---------------- fused: scatter -> barrier -> diag3 -> cascade tail --------
// Coherence: cross-block-visible writes (entp, ND, gsum) are agent-scope
// write-through (MALL truth, no dirty L2 anywhere); cnt via device RMW; bulk
// entp reuse reads are normal loads (written only pre-barrier; dispatch-start
// invalidate killed stale replay lines). NO threadfence (R4: L2 flush = 425us).
__global__ __launch_bounds__(256, 4) void fused_kernel(
        const int* __restrict__ idx, const float* __restrict__ wgt, int m,
        const int* __restrict__ lst, int nl,
        int* __restrict__ cnt, unsigned* __restrict__ entp,
        unsigned long long* __restrict__ ND, double* __restrict__ gsum,
        int* __restrict__ ctr, float* __restrict__ out) {
    __shared__ float    lrow[NN];       // 16 KB dense image of current row
    __shared__ unsigned witem[2 * CAP]; // entp base index per 64-entry chunk
    __shared__ float    wa[2 * CAP];    // aij per chunk
    __shared__ int      nit;
    __shared__ float    red[8];
    __shared__ int      flag;
    __shared__ double   dsum[4][4];
    __shared__ double   wb[2];
    __shared__ double   sh[4];

    const int tid  = threadIdx.x;
    const int bid  = blockIdx.x;
    const int gtid = bid * 256 + tid;
    const int warp = tid >> 6, lane = tid & 63;

    // ---- P1: scatter edges, symmetrized (s,d)+(d,s), duplicates kept raw ----
    // A = scatter + A^T - diag(diag): row s gets (d,w), row d gets (s,w) once.
    if (gtid < m) {
        int2 sd = ((const int2*)idx)[gtid];
        int s = sd.x, d = sd.y;
        unsigned ival = (unsigned)(int)wgt[gtid];
        if (ival > 255u) ival = 255u;
        int p = atomicAdd(cnt + s, 1);          // device-scope RMW at MALL
        if (p < CAP)
            __hip_atomic_store(entp + (size_t)s * CAP + p, ((unsigned)d << 8) | ival,
                               __ATOMIC_RELAXED, __HIP_MEMORY_SCOPE_AGENT);
        if (s != d) {
            int q = atomicAdd(cnt + d, 1);
            if (q < CAP)
                __hip_atomic_store(entp + (size_t)d * CAP + q, ((unsigned)s << 8) | ival,
                                   __ATOMIC_RELAXED, __HIP_MEMORY_SCOPE_AGENT);
        }
    }
    gridbar(ctr, tid, bid);

    // ---- P2: diag(A^3)_i + rowsum, 4 rows per block (R10 interior) ----------
    // diag(A^3)_i = sum_{(j,w) in row i} w * sum_{(k,w') in row j} w' * A_ik;
    // A_ik from dense LDS image (LDS atomicAdd merge; exact int f32 adds ->
    // order-independent -> deterministic).
    {
        const int i0 = bid * RPB;
        float4* l4 = (float4*)lrow;
        unsigned pk = 0u;
        if (tid < CAP) pk = entp[(size_t)i0 * CAP + tid];

        for (int rr = 0; rr < RPB; ++rr) {
            const int i = i0 + rr;
            for (int k = tid; k < NN4; k += 256) l4[k] = make_float4(0.f, 0.f, 0.f, 0.f);
            if (tid == 0) nit = 0;
            __syncthreads();

            float vv = 0.f;
            if (tid < CAP) {
                vv = (float)(pk & 0xffu);
                if (vv > 0.f) {
                    int col = pk >> 8;
                    atomicAdd(&lrow[col], vv);           // LDS merge (exact)
                    int slot = atomicAdd(&nit, 2);
                    unsigned base = (unsigned)col * CAP;
                    witem[slot]     = base;      wa[slot]     = vv;
                    witem[slot + 1] = base + 64; wa[slot + 1] = vv;
                }
            }
            float nsum = vv;
            for (int o = 32; o; o >>= 1) nsum += __shfl_down(nsum, o);
            if (lane == 0) red[warp] = nsum;
            __syncthreads();
            const int NIT = nit;

            unsigned pknext = 0u;
            if (rr + 1 < RPB && tid < CAP) pknext = entp[(size_t)(i + 1) * CAP + tid];
            asm volatile("" : "+v"(pknext));

            float acc = 0.f;
            for (int t = warp; t < NIT; t += 16) {
                const int t1 = t + 4, t2 = t + 8, t3 = t + 12;
                const bool b1 = t1 < NIT, b2 = t2 < NIT, b3 = t3 < NIT;
                unsigned u0 = witem[t];
                unsigned u1 = b1 ? witem[t1] : 0u;
                unsigned u2 = b2 ? witem[t2] : 0u;
                unsigned u3 = b3 ? witem[t3] : 0u;
                float a0 = wa[t];
                float a1 = b1 ? wa[t1] : 0.f;
                float a2 = b2 ? wa[t2] : 0.f;
                float a3 = b3 ? wa[t3] : 0.f;
                unsigned q0 = entp[u0 + lane];   // normal loads: L2-resident reuse
                unsigned q1 = entp[u1 + lane];
                unsigned q2 = entp[u2 + lane];
                unsigned q3 = entp[u3 + lane];
                float d0 = (float)(q0 & 0xffu) * lrow[q0 >> 8];
                float d1 = (float)(q1 & 0xffu) * lrow[q1 >> 8];
                float d2 = (float)(q2 & 0xffu) * lrow[q2 >> 8];
                float d3 = (float)(q3 & 0xffu) * lrow[q3 >> 8];
                acc += a0 * d0 + a1 * d1 + a2 * d2 + a3 * d3;
            }
            for (int o = 32; o; o >>= 1) acc += __shfl_down(acc, o);
            if (lane == 0) red[4 + warp] = acc;
            __syncthreads();

            if (tid == 0) {
                float2 nd = make_float2(red[0] + red[1] + red[2] + red[3],
                                        red[4] + red[5] + red[6] + red[7]);
                unsigned long long bits;
                __builtin_memcpy(&bits, &nd, 8);
                __hip_atomic_store(ND + i, bits, __ATOMIC_RELAXED, __HIP_MEMORY_SCOPE_AGENT);
            }
            pk = pknext;
        }
    }

    // ---- cascade tail (non-blocking; only finishers continue) --------------
    if (tid == 0) {
        asm volatile("s_waitcnt vmcnt(0)" ::: "memory");  // drain 4 ND stores
        int v = __hip_atomic_fetch_add(ctr + C_TGRP + (bid >> 6) * GPAD, 1,
                                       __ATOMIC_RELAXED, __HIP_MEMORY_SCOPE_AGENT);
        flag = (v == 63);
    }
    __syncthreads();
    if (!flag) return;

    // group finisher: all 256 threads, one row each -> fp64 OLS partials
    const int g = bid >> 6;
    {
        int r = g * 256 + tid;
        unsigned long long bits = __hip_atomic_load(ND + r, __ATOMIC_RELAXED,
                                                    __HIP_MEMORY_SCOPE_AGENT);
        float2 nd; __builtin_memcpy(&nd, &bits, 8);
        double Nd = (double)nd.x;
        double Ed = Nd + 0.5 * (double)nd.y;
        double ln = (double)logf((float)(Nd + 1e-20));
        double le = (double)logf((float)(Ed + 1e-20));
        double p1 = ln, p2 = ln * ln, p3 = le, p4 = ln * le;
        for (int o = 32; o; o >>= 1) {
            p1 += __shfl_down(p1, o);
            p2 += __shfl_down(p2, o);
            p3 += __shfl_down(p3, o);
            p4 += __shfl_down(p4, o);
        }
        if (lane == 0) {
            dsum[warp][0] = p1; dsum[warp][1] = p2;
            dsum[warp][2] = p3; dsum[warp][3] = p4;
        }
        __syncthreads();
        if (tid == 0) {
            for (int k = 0; k < 4; ++k) {
                double v = dsum[0][k] + dsum[1][k] + dsum[2][k] + dsum[3][k];
                __hip_atomic_store(gsum + g * 4 + k, v, __ATOMIC_RELAXED,
                                   __HIP_MEMORY_SCOPE_AGENT);
            }
            asm volatile("s_waitcnt vmcnt(0)" ::: "memory");
            int vg = __hip_atomic_fetch_add(ctr + C_TGLOB, 1,
                                            __ATOMIC_RELAXED, __HIP_MEMORY_SCOPE_AGENT);
            flag = (vg == NGRP - 1);
        }
    }
    __syncthreads();
    if (!flag) return;

    // global finisher: sum 16 partials, solve 2x2, residual over targets
    if (warp == 0) {
        double s1 = 0, s2 = 0, t0 = 0, t1 = 0;
        if (lane < NGRP) {
            s1 = __hip_atomic_load(gsum + lane * 4 + 0, __ATOMIC_RELAXED, __HIP_MEMORY_SCOPE_AGENT);
            s2 = __hip_atomic_load(gsum + lane * 4 + 1, __ATOMIC_RELAXED, __HIP_MEMORY_SCOPE_AGENT);
            t0 = __hip_atomic_load(gsum + lane * 4 + 2, __ATOMIC_RELAXED, __HIP_MEMORY_SCOPE_AGENT);
            t1 = __hip_atomic_load(gsum + lane * 4 + 3, __ATOMIC_RELAXED, __HIP_MEMORY_SCOPE_AGENT);
        }
        for (int o = 32; o; o >>= 1) {
            s1 += __shfl_down(s1, o);
            s2 += __shfl_down(s2, o);
            t0 += __shfl_down(t0, o);
            t1 += __shfl_down(t1, o);
        }
        if (lane == 0) {
            double n = (double)NN;
            double det = n * s2 - s1 * s1;
            wb[0] = (n * t1 - s1 * t0) / det;   // w
            wb[1] = (s2 * t0 - s1 * t1) / det;  // b
        }
    }
    __syncthreads();
    const double w = wb[0];
    const double eb = exp(wb[1]);
    const float wf = (float)w;
    double racc = 0;
    for (int p = tid; p < nl; p += 256) {
        int r = lst[p];
        unsigned long long bits = __hip_atomic_load(ND + r, __ATOMIC_RELAXED,
                                                    __HIP_MEMORY_SCOPE_AGENT);
        float2 nd; __builtin_memcpy(&nd, &bits, 8);
        double Nd = (double)nd.x;
        double Ed = Nd + 0.5 * (double)nd.y;
        double pr = (nd.x > 0.f) ? (double)exp2f(wf * log2f(nd.x)) : 0.0;
        double rv = eb * pr - Ed;
        racc += rv * rv;
    }
    for (int o = 32; o; o >>= 1) racc += __shfl_down(racc, o);
    if (lane == 0) sh[warp] = racc;
    __syncthreads();
    if (tid == 0) out[0] = (float)(sh[0] + sh[1] + sh[2] + sh[3]);
}

extern "C" void kernel_launch(void* const* d_in, const int* in_sizes, int n_in,
                              void* d_out, int out_size, void* d_ws, size_t ws_size,
                              hipStream_t stream) {
    const int*   tri_idx = (const int*)d_in[0];
    const float* tri_w   = (const float*)d_in[1];
    const int*   lst     = (const int*)d_in[2];
    const int m  = in_sizes[1];          // number of edges
    const int nl = in_sizes[2];          // number of targets

    char* base = (char*)d_ws;
    int*      ctr  = (int*)base;
    int*      cnt  = (int*)(base + OFF_CNT);
    unsigned* entp = (unsigned*)(base + OFF_ENTP);
    unsigned long long* ND = (unsigned long long*)(base + OFF_ND);
    double*   gsum = (double*)(base + OFF_GSUM);
    float*    out  = (float*)d_out;

    zeroall_kernel<<<(Z4 + 255) / 256, 256, 0, stream>>>((float4*)base);
    fused_kernel<<<D3B, 256, 0, stream>>>(tri_idx, tri_w, m, lst, nl,
                                          cnt, entp, ND, gsum, ctr, out);
}

// Round 13
// 57.151 us; speedup vs baseline: 3.4489x; 1.0367x over previous
//
#include <hip/hip_runtime.h>
#include <math.h>

#define NN   4096
#define NN4  (NN/4)
#define CAP  128      // slots per row; Poisson(64) -> 128 = 8 sigma, never hit
#define RPB  4        // rows per block in diag3 phase
#define D3B  (NN/RPB) // 1024 blocks: 4/CU needed, 8/CU LDS capacity -> co-resident
#define NGRP 16       // barrier/tail groups
#define GPAD 32       // ints per counter line (128 B)

// ---- workspace layout (bytes from d_ws) ----
#define OFF_CNT  4608
#define OFF_ENTP 20992
#define OFF_ND   2118144
#define OFF_GSUM 2150912
#define ZBYTES   OFF_ND            // zero ctr+cnt+entp (ND/gsum fully overwritten)
#define Z4       (ZBYTES / 16)

// counter indices (ints)
#define C_GO    0
#define C_BGRP  (1 * GPAD)         // 16 lines
#define C_BGLOB (17 * GPAD)
#define C_TGRP  (18 * GPAD)        // 16 lines
#define C_TGLOB (34 * GPAD)

// ---------------- bootstrap: zero ctr + cnt + entp ----------------
// Separate dispatch: end-of-kernel writeback + next dispatch's invalidate give
// coherence for free. Zero-filled entp is load-bearing (R10): empty slots
// decode to (col 0, w 0) -> contribute exactly 0 -> no masking in inner loop.
__global__ __launch_bounds__(256) void zeroall_kernel(float4* __restrict__ z) {
    int t = blockIdx.x * 256 + threadIdx.x;
    if (t < Z4) z[t] = make_float4(0.f, 0.f, 0.f, 0.f);
}

// Two-level grid barrier with broadcast release (R12, works: ~2-3us).
// R11 lesson: same-line RMW arrivals serialize at MALL; spread over 16 lines,
// release via one go word polled read-only.
__device__ __forceinline__ void gridbar(int* __restrict__ c, int tid, int bid) {
    __syncthreads();
    if (tid == 0) {
        int v = __hip_atomic_fetch_add(c + C_BGRP + (bid & 15) * GPAD, 1,
                                       __ATOMIC_RELAXED, __HIP_MEMORY_SCOPE_AGENT);
        if (v == 63) {
            int vg = __hip_atomic_fetch_add(c + C_BGLOB, 1,
                                            __ATOMIC_RELAXED, __HIP_MEMORY_SCOPE_AGENT);
            if (vg == NGRP - 1)
                __hip_atomic_store(c + C_GO, 1, __ATOMIC_RELAXED, __HIP_MEMORY_SCOPE_AGENT);
        }
        while (__hip_atomic_load(c + C_GO, __ATOMIC_RELAXED, __HIP_MEMORY_SCOPE_AGENT) == 0)
            __builtin_amdgcn_s_sleep(8);
    }
    __syncthreads();
}

// ---------------- fused: scatter -> barrier -> diag3 -> cascade tail --------
// Coherence discipline (R11/R12): cross-block-visible writes (entp, ND, gsum)
// are agent-scope write-through; cnt via device RMW (MALL) and read back with
// agent loads; bulk entp reads are normal loads (first normal touch post-
// barrier pulls fresh lines from MALL). NO threadfence (R4: L2 flush = 425us).
// R13 interior: entries occupy slots 0..cnt-1 contiguously -> no compaction
// queue, no LDS nit atomics; one dwordx2 load covers a whole neighbor row.
__global__ __launch_bounds__(256, 4) void fused_kernel(
        const int* __restrict__ idx, const float* __restrict__ wgt, int m,
        const int* __restrict__ lst, int nl,
        int* __restrict__ cnt, unsigned* __restrict__ entp,
        unsigned long long* __restrict__ ND, double* __restrict__ gsum,
        int* __restrict__ ctr, float* __restrict__ out) {
    __shared__ float    lrow[NN];    // 16 KB dense image of current row
    __shared__ int      lcol[CAP];   // decoded cols of row i (slot-indexed)
    __shared__ float    lval[CAP];   // decoded weights of row i
    __shared__ float    red[8];
    __shared__ int      flag;
    __shared__ double   dsum[4][4];
    __shared__ double   wb[2];
    __shared__ double   sh[4];

    const int tid  = threadIdx.x;
    const int bid  = blockIdx.x;
    const int gtid = bid * 256 + tid;
    const int warp = tid >> 6, lane = tid & 63;

    // ---- P1: scatter edges, symmetrized (s,d)+(d,s), duplicates kept raw ----
    // A = scatter + A^T - diag(diag): row s gets (d,w), row d gets (s,w) once.
    if (gtid < m) {
        int2 sd = ((const int2*)idx)[gtid];
        int s = sd.x, d = sd.y;
        unsigned ival = (unsigned)(int)wgt[gtid];
        if (ival > 255u) ival = 255u;
        int p = atomicAdd(cnt + s, 1);          // device-scope RMW at MALL
        if (p < CAP)
            __hip_atomic_store(entp + (size_t)s * CAP + p, ((unsigned)d << 8) | ival,
                               __ATOMIC_RELAXED, __HIP_MEMORY_SCOPE_AGENT);
        if (s != d) {
            int q = atomicAdd(cnt + d, 1);
            if (q < CAP)
                __hip_atomic_store(entp + (size_t)d * CAP + q, ((unsigned)s << 8) | ival,
                                   __ATOMIC_RELAXED, __HIP_MEMORY_SCOPE_AGENT);
        }
    }
    gridbar(ctr, tid, bid);

    // ---- P2: diag(A^3)_i + rowsum, 4 rows per block -------------------------
    // diag(A^3)_i = sum_{(j,w) in row i} w * sum_{(k,w') in row j} w' * A_ik;
    // A_ik from dense LDS image (LDS atomicAdd merge; exact int f32 adds ->
    // order-independent -> deterministic).
    {
        const int i0 = bid * RPB;
        float4* l4 = (float4*)lrow;

        // prefetch the block's row counts (agent loads: bypass stale caches)
        int mi_arr[RPB];
        #pragma unroll
        for (int r = 0; r < RPB; ++r) {
            int c = __hip_atomic_load(cnt + i0 + r, __ATOMIC_RELAXED,
                                      __HIP_MEMORY_SCOPE_AGENT);
            mi_arr[r] = c > CAP ? CAP : c;
        }
        // prefetch row 0's entries
        unsigned pk = 0u;
        if (tid < CAP) pk = entp[(size_t)i0 * CAP + tid];

        for (int rr = 0; rr < RPB; ++rr) {
            const int i = i0 + rr;
            const int mi = mi_arr[rr];
            for (int k = tid; k < NN4; k += 256) l4[k] = make_float4(0.f, 0.f, 0.f, 0.f);
            __syncthreads();

            float vv = 0.f;
            if (tid < CAP) {
                int col = pk >> 8;
                vv = (float)(pk & 0xffu);
                lcol[tid] = col;
                lval[tid] = vv;
                atomicAdd(&lrow[col], vv);   // branchless: empty slots add 0 to lrow[0]
            }
            float nsum = vv;
            for (int o = 32; o; o >>= 1) nsum += __shfl_down(nsum, o);
            if (lane == 0) red[warp] = nsum;
            __syncthreads();

            // prefetch next row's entries; keep hoisted above the inner loop
            unsigned pknext = 0u;
            if (rr + 1 < RPB && tid < CAP) pknext = entp[(size_t)(i + 1) * CAP + tid];
            asm volatile("" : "+v"(pknext));

            // ---- inner: one dwordx2 (whole 512 B neighbor row) per item,
            //      4 items in flight per wave ----
            float acc = 0.f;
            for (int t = warp; t < mi; t += 16) {
                const int t1 = t + 4, t2 = t + 8, t3 = t + 12;
                const bool b1 = t1 < mi, b2 = t2 < mi, b3 = t3 < mi;
                int   c0 = lcol[t];
                int   c1 = b1 ? lcol[t1] : 0;
                int   c2 = b2 ? lcol[t2] : 0;
                int   c3 = b3 ? lcol[t3] : 0;
                float a0 = lval[t];
                float a1 = b1 ? lval[t1] : 0.f;
                float a2 = b2 ? lval[t2] : 0.f;
                float a3 = b3 ? lval[t3] : 0.f;
                uint2 q0 = ((const uint2*)(entp + (size_t)c0 * CAP))[lane];
                uint2 q1 = ((const uint2*)(entp + (size_t)c1 * CAP))[lane];
                uint2 q2 = ((const uint2*)(entp + (size_t)c2 * CAP))[lane];
                uint2 q3 = ((const uint2*)(entp + (size_t)c3 * CAP))[lane];
                float d0 = (float)(q0.x & 0xffu) * lrow[q0.x >> 8]
                         + (float)(q0.y & 0xffu) * lrow[q0.y >> 8];
                float d1 = (float)(q1.x & 0xffu) * lrow[q1.x >> 8]
                         + (float)(q1.y & 0xffu) * lrow[q1.y >> 8];
                float d2 = (float)(q2.x & 0xffu) * lrow[q2.x >> 8]
                         + (float)(q2.y & 0xffu) * lrow[q2.y >> 8];
                float d3 = (float)(q3.x & 0xffu) * lrow[q3.x >> 8]
                         + (float)(q3.y & 0xffu) * lrow[q3.y >> 8];
                acc += a0 * d0 + a1 * d1 + a2 * d2 + a3 * d3;
            }
            for (int o = 32; o; o >>= 1) acc += __shfl_down(acc, o);
            if (lane == 0) red[4 + warp] = acc;
            __syncthreads();

            if (tid == 0) {
                float2 nd = make_float2(red[0] + red[1] + red[2] + red[3],
                                        red[4] + red[5] + red[6] + red[7]);
                unsigned long long bits;
                __builtin_memcpy(&bits, &nd, 8);
                __hip_atomic_store(ND + i, bits, __ATOMIC_RELAXED, __HIP_MEMORY_SCOPE_AGENT);
            }
            pk = pknext;
            __syncthreads();   // lrow reads done before next row's zeroing
        }
    }

    // ---- cascade tail (non-blocking; only finishers continue) --------------
    if (tid == 0) {
        asm volatile("s_waitcnt vmcnt(0)" ::: "memory");  // drain 4 ND stores
        int v = __hip_atomic_fetch_add(ctr + C_TGRP + (bid >> 6) * GPAD, 1,
                                       __ATOMIC_RELAXED, __HIP_MEMORY_SCOPE_AGENT);
        flag = (v == 63);
    }
    __syncthreads();
    if (!flag) return;

    // group finisher: 256 threads, one row each -> fp64 OLS partials
    const int g = bid >> 6;
    {
        int r = g * 256 + tid;
        unsigned long long bits = __hip_atomic_load(ND + r, __ATOMIC_RELAXED,
                                                    __HIP_MEMORY_SCOPE_AGENT);
        float2 nd; __builtin_memcpy(&nd, &bits, 8);
        double Nd = (double)nd.x;
        double Ed = Nd + 0.5 * (double)nd.y;
        double ln = (double)logf((float)(Nd + 1e-20));
        double le = (double)logf((float)(Ed + 1e-20));
        double p1 = ln, p2 = ln * ln, p3 = le, p4 = ln * le;
        for (int o = 32; o; o >>= 1) {
            p1 += __shfl_down(p1, o);
            p2 += __shfl_down(p2, o);
            p3 += __shfl_down(p3, o);
            p4 += __shfl_down(p4, o);
        }
        if (lane == 0) {
            dsum[warp][0] = p1; dsum[warp][1] = p2;
            dsum[warp][2] = p3; dsum[warp][3] = p4;
        }
        __syncthreads();
        if (tid == 0) {
            for (int k = 0; k < 4; ++k) {
                double v = dsum[0][k] + dsum[1][k] + dsum[2][k] + dsum[3][k];
                __hip_atomic_store(gsum + g * 4 + k, v, __ATOMIC_RELAXED,
                                   __HIP_MEMORY_SCOPE_AGENT);
            }
            asm volatile("s_waitcnt vmcnt(0)" ::: "memory");
            int vg = __hip_atomic_fetch_add(ctr + C_TGLOB, 1,
                                            __ATOMIC_RELAXED, __HIP_MEMORY_SCOPE_AGENT);
            flag = (vg == NGRP - 1);
        }
    }
    __syncthreads();
    if (!flag) return;

    // global finisher: sum 16 partials, solve 2x2, residual over targets
    if (warp == 0) {
        double s1 = 0, s2 = 0, t0 = 0, t1 = 0;
        if (lane < NGRP) {
            s1 = __hip_atomic_load(gsum + lane * 4 + 0, __ATOMIC_RELAXED, __HIP_MEMORY_SCOPE_AGENT);
            s2 = __hip_atomic_load(gsum + lane * 4 + 1, __ATOMIC_RELAXED, __HIP_MEMORY_SCOPE_AGENT);
            t0 = __hip_atomic_load(gsum + lane * 4 + 2, __ATOMIC_RELAXED, __HIP_MEMORY_SCOPE_AGENT);
            t1 = __hip_atomic_load(gsum + lane * 4 + 3, __ATOMIC_RELAXED, __HIP_MEMORY_SCOPE_AGENT);
        }
        for (int o = 32; o; o >>= 1) {
            s1 += __shfl_down(s1, o);
            s2 += __shfl_down(s2, o);
            t0 += __shfl_down(t0, o);
            t1 += __shfl_down(t1, o);
        }
        if (lane == 0) {
            double n = (double)NN;
            double det = n * s2 - s1 * s1;
            wb[0] = (n * t1 - s1 * t0) / det;   // w
            wb[1] = (s2 * t0 - s1 * t1) / det;  // b
        }
    }
    __syncthreads();
    const double w = wb[0];
    const double eb = exp(wb[1]);
    const float wf = (float)w;
    double racc = 0;
    for (int p = tid; p < nl; p += 256) {
        int r = lst[p];
        unsigned long long bits = __hip_atomic_load(ND + r, __ATOMIC_RELAXED,
                                                    __HIP_MEMORY_SCOPE_AGENT);
        float2 nd; __builtin_memcpy(&nd, &bits, 8);
        double Nd = (double)nd.x;
        double Ed = Nd + 0.5 * (double)nd.y;
        double pr = (nd.x > 0.f) ? (double)exp2f(wf * log2f(nd.x)) : 0.0;
        double rv = eb * pr - Ed;
        racc += rv * rv;
    }
    for (int o = 32; o; o >>= 1) racc += __shfl_down(racc, o);
    if (lane == 0) sh[warp] = racc;
    __syncthreads();
    if (tid == 0) out[0] = (float)(sh[0] + sh[1] + sh[2] + sh[3]);
}

extern "C" void kernel_launch(void* const* d_in, const int* in_sizes, int n_in,
                              void* d_out, int out_size, void* d_ws, size_t ws_size,
                              hipStream_t stream) {
    const int*   tri_idx = (const int*)d_in[0];
    const float* tri_w   = (const float*)d_in[1];
    const int*   lst     = (const int*)d_in[2];
    const int m  = in_sizes[1];          // number of edges
    const int nl = in_sizes[2];          // number of targets

    char* base = (char*)d_ws;
    int*      ctr  = (int*)base;
    int*      cnt  = (int*)(base + OFF_CNT);
    unsigned* entp = (unsigned*)(base + OFF_ENTP);
    unsigned long long* ND = (unsigned long long*)(base + OFF_ND);
    double*   gsum = (double*)(base + OFF_GSUM);
    float*    out  = (float*)d_out;

    zeroall_kernel<<<(Z4 + 255) / 256, 256, 0, stream>>>((float4*)base);
    fused_kernel<<<D3B, 256, 0, stream>>>(tri_idx, tri_w, m, lst, nl,
                                          cnt, entp, ND, gsum, ctr, out);
}

// Round 14
// 50.611 us; speedup vs baseline: 3.8946x; 1.1292x over previous
//
#include <hip/hip_runtime.h>
#include <math.h>

#define NN   4096
#define NN4  (NN/4)
#define CAP  128      // slots per row; Poisson(64) -> 128 = 8 sigma, never hit
#define RPB  4        // rows per block in diag3 phase
#define D3B  (NN/RPB) // 1024 blocks: 4/CU needed, 8/CU LDS capacity -> co-resident
#define NGRP 16       // barrier/tail groups
#define GPAD 32       // ints per counter line (128 B)
#define CPAD 32       // ints per scatter counter (128 B) -- R14: line-per-counter

// counter indices (ints from ctr base)
#define C_GO    0                  // 16 release lines (R14: kill poll storm)
#define C_BGRP  (16 * GPAD)        // 16 arrival lines
#define C_BGLOB (32 * GPAD)
#define C_TGRP  (33 * GPAD)        // 16 tail lines
#define C_TGLOB (49 * GPAD)

// ---- workspace layout (bytes from d_ws) ----
// ctr  @ 0       : 50*GPAD i32 (6.4 KB)
// cnt  @ 6656    : NN*CPAD i32 (512 KB)   one counter per 128 B line
// entp @ 530944  : NN*CAP u32 (2 MiB)     packed col<<8|w entries (ZEROED)
// ND   @ 2628096 : NN u64 (32 KB)         packed float2 {N, D3}
// gsum @ 2660864 : NGRP*4 f64 (512 B)
#define OFF_CNT  6656
#define OFF_ENTP 530944
#define OFF_ND   2628096
#define OFF_GSUM 2660864
#define ZBYTES   OFF_ND            // zero ctr+cnt+entp (ND/gsum fully overwritten)
#define Z4       (ZBYTES / 16)

// ---------------- bootstrap: zero ctr + cnt + entp ----------------
// Separate dispatch: end-of-kernel writeback-invalidate + next dispatch's
// acquire give coherence for free. Zero-filled entp is load-bearing (R10):
// empty slots decode to (col 0, w 0) -> contribute exactly 0, no masking.
__global__ __launch_bounds__(256) void zeroall_kernel(float4* __restrict__ z) {
    int t = blockIdx.x * 256 + threadIdx.x;
    if (t < Z4) z[t] = make_float4(0.f, 0.f, 0.f, 0.f);
}

// Two-level grid barrier, fully line-spread (R5/R11/R14 lessons):
// arrivals over 16 lines (<=64 RMWs each, parallel), release over 16 go lines
// (<=64 read-only pollers each -- one hot line saturates its MALL channel).
__device__ __forceinline__ void gridbar(int* __restrict__ c, int tid, int bid) {
    __syncthreads();   // waves drain their stores (vmcnt) before s_barrier
    if (tid == 0) {
        const int g = bid & 15;
        int v = __hip_atomic_fetch_add(c + C_BGRP + g * GPAD, 1,
                                       __ATOMIC_RELAXED, __HIP_MEMORY_SCOPE_AGENT);
        if (v == 63) {
            int vg = __hip_atomic_fetch_add(c + C_BGLOB, 1,
                                            __ATOMIC_RELAXED, __HIP_MEMORY_SCOPE_AGENT);
            if (vg == NGRP - 1) {
                #pragma unroll
                for (int k = 0; k < 16; ++k)
                    __hip_atomic_store(c + C_GO + k * GPAD, 1,
                                       __ATOMIC_RELAXED, __HIP_MEMORY_SCOPE_AGENT);
            }
        }
        while (__hip_atomic_load(c + C_GO + g * GPAD,
                                 __ATOMIC_RELAXED, __HIP_MEMORY_SCOPE_AGENT) == 0)
            __builtin_amdgcn_s_sleep(8);
    }
    __syncthreads();
}

// ---------------- fused: scatter -> barrier -> diag3 -> cascade tail --------
// Coherence discipline (R11-R13, verified passing): cross-block-visible writes
// (entp, ND, gsum) are agent-scope write-through; cnt via device RMW at MALL,
// read back with agent loads; bulk entp reads are normal loads (L2 invalidated
// at dispatch start; first touch pulls from MALL). NO threadfence (R4).
__global__ __launch_bounds__(256, 4) void fused_kernel(
        const int* __restrict__ idx, const float* __restrict__ wgt, int m,
        const int* __restrict__ lst, int nl,
        int* __restrict__ cnt, unsigned* __restrict__ entp,
        unsigned long long* __restrict__ ND, double* __restrict__ gsum,
        int* __restrict__ ctr, float* __restrict__ out) {
    __shared__ float    lrow[NN];    // 16 KB dense image of current row
    __shared__ int      lcol[CAP];   // decoded cols of row i (slot-indexed)
    __shared__ float    lval[CAP];   // decoded weights of row i
    __shared__ float    red[8];
    __shared__ int      flag;
    __shared__ double   dsum[4][4];
    __shared__ double   wb[2];
    __shared__ double   sh[4];

    const int tid  = threadIdx.x;
    const int bid  = blockIdx.x;
    const int gtid = bid * 256 + tid;
    const int warp = tid >> 6, lane = tid & 63;

    // ---- P1: scatter edges, symmetrized (s,d)+(d,s), duplicates kept raw ----
    // A = scatter + A^T - diag(diag): row s gets (d,w), row d gets (s,w) once.
    // R14: cnt padded to a 128 B line per counter -- R13's 16 counters/line
    // made 262K RMWs serialize ~1024-deep per line (R5 arithmetic: ~15-20us).
    if (gtid < m) {
        int2 sd = ((const int2*)idx)[gtid];
        int s = sd.x, d = sd.y;
        unsigned ival = (unsigned)(int)wgt[gtid];
        if (ival > 255u) ival = 255u;
        int p = atomicAdd(cnt + s * CPAD, 1);     // device RMW, private line
        if (p < CAP)
            __hip_atomic_store(entp + (size_t)s * CAP + p, ((unsigned)d << 8) | ival,
                               __ATOMIC_RELAXED, __HIP_MEMORY_SCOPE_AGENT);
        if (s != d) {
            int q = atomicAdd(cnt + d * CPAD, 1);
            if (q < CAP)
                __hip_atomic_store(entp + (size_t)d * CAP + q, ((unsigned)s << 8) | ival,
                                   __ATOMIC_RELAXED, __HIP_MEMORY_SCOPE_AGENT);
        }
    }
    gridbar(ctr, tid, bid);

    // ---- P2: diag(A^3)_i + rowsum, 4 rows per block (R13 interior) ----------
    // diag(A^3)_i = sum_{(j,w) in row i} w * sum_{(k,w') in row j} w' * A_ik;
    // A_ik from dense LDS image (LDS atomicAdd merge; exact int f32 adds ->
    // order-independent -> deterministic).
    {
        const int i0 = bid * RPB;
        float4* l4 = (float4*)lrow;

        int mi_arr[RPB];
        #pragma unroll
        for (int r = 0; r < RPB; ++r) {
            int c = __hip_atomic_load(cnt + (i0 + r) * CPAD, __ATOMIC_RELAXED,
                                      __HIP_MEMORY_SCOPE_AGENT);
            mi_arr[r] = c > CAP ? CAP : c;
        }
        unsigned pk = 0u;
        if (tid < CAP) pk = entp[(size_t)i0 * CAP + tid];

        for (int rr = 0; rr < RPB; ++rr) {
            const int i = i0 + rr;
            const int mi = mi_arr[rr];
            for (int k = tid; k < NN4; k += 256) l4[k] = make_float4(0.f, 0.f, 0.f, 0.f);
            __syncthreads();

            float vv = 0.f;
            if (tid < CAP) {
                int col = pk >> 8;
                vv = (float)(pk & 0xffu);
                lcol[tid] = col;
                lval[tid] = vv;
                atomicAdd(&lrow[col], vv);   // branchless: empty slots add 0 to lrow[0]
            }
            float nsum = vv;
            for (int o = 32; o; o >>= 1) nsum += __shfl_down(nsum, o);
            if (lane == 0) red[warp] = nsum;
            __syncthreads();

            unsigned pknext = 0u;
            if (rr + 1 < RPB && tid < CAP) pknext = entp[(size_t)(i + 1) * CAP + tid];
            asm volatile("" : "+v"(pknext));

            // one dwordx2 (whole 512 B neighbor row) per item, 4 in flight/wave
            float acc = 0.f;
            for (int t = warp; t < mi; t += 16) {
                const int t1 = t + 4, t2 = t + 8, t3 = t + 12;
                const bool b1 = t1 < mi, b2 = t2 < mi, b3 = t3 < mi;
                int   c0 = lcol[t];
                int   c1 = b1 ? lcol[t1] : 0;
                int   c2 = b2 ? lcol[t2] : 0;
                int   c3 = b3 ? lcol[t3] : 0;
                float a0 = lval[t];
                float a1 = b1 ? lval[t1] : 0.f;
                float a2 = b2 ? lval[t2] : 0.f;
                float a3 = b3 ? lval[t3] : 0.f;
                uint2 q0 = ((const uint2*)(entp + (size_t)c0 * CAP))[lane];
                uint2 q1 = ((const uint2*)(entp + (size_t)c1 * CAP))[lane];
                uint2 q2 = ((const uint2*)(entp + (size_t)c2 * CAP))[lane];
                uint2 q3 = ((const uint2*)(entp + (size_t)c3 * CAP))[lane];
                float d0 = (float)(q0.x & 0xffu) * lrow[q0.x >> 8]
                         + (float)(q0.y & 0xffu) * lrow[q0.y >> 8];
                float d1 = (float)(q1.x & 0xffu) * lrow[q1.x >> 8]
                         + (float)(q1.y & 0xffu) * lrow[q1.y >> 8];
                float d2 = (float)(q2.x & 0xffu) * lrow[q2.x >> 8]
                         + (float)(q2.y & 0xffu) * lrow[q2.y >> 8];
                float d3 = (float)(q3.x & 0xffu) * lrow[q3.x >> 8]
                         + (float)(q3.y & 0xffu) * lrow[q3.y >> 8];
                acc += a0 * d0 + a1 * d1 + a2 * d2 + a3 * d3;
            }
            for (int o = 32; o; o >>= 1) acc += __shfl_down(acc, o);
            if (lane == 0) red[4 + warp] = acc;
            __syncthreads();

            if (tid == 0) {
                float2 nd = make_float2(red[0] + red[1] + red[2] + red[3],
                                        red[4] + red[5] + red[6] + red[7]);
                unsigned long long bits;
                __builtin_memcpy(&bits, &nd, 8);
                __hip_atomic_store(ND + i, bits, __ATOMIC_RELAXED, __HIP_MEMORY_SCOPE_AGENT);
            }
            pk = pknext;
            __syncthreads();   // lrow reads done before next row's zeroing
        }
    }

    // ---- cascade tail (non-blocking; only finishers continue) --------------
    if (tid == 0) {
        asm volatile("s_waitcnt vmcnt(0)" ::: "memory");  // drain 4 ND stores
        int v = __hip_atomic_fetch_add(ctr + C_TGRP + (bid >> 6) * GPAD, 1,
                                       __ATOMIC_RELAXED, __HIP_MEMORY_SCOPE_AGENT);
        flag = (v == 63);
    }
    __syncthreads();
    if (!flag) return;

    // group finisher: 256 threads, one row each -> fp64 OLS partials
    const int g = bid >> 6;
    {
        int r = g * 256 + tid;
        unsigned long long bits = __hip_atomic_load(ND + r, __ATOMIC_RELAXED,
                                                    __HIP_MEMORY_SCOPE_AGENT);
        float2 nd; __builtin_memcpy(&nd, &bits, 8);
        double Nd = (double)nd.x;
        double Ed = Nd + 0.5 * (double)nd.y;
        double ln = (double)logf((float)(Nd + 1e-20));
        double le = (double)logf((float)(Ed + 1e-20));
        double p1 = ln, p2 = ln * ln, p3 = le, p4 = ln * le;
        for (int o = 32; o; o >>= 1) {
            p1 += __shfl_down(p1, o);
            p2 += __shfl_down(p2, o);
            p3 += __shfl_down(p3, o);
            p4 += __shfl_down(p4, o);
        }
        if (lane == 0) {
            dsum[warp][0] = p1; dsum[warp][1] = p2;
            dsum[warp][2] = p3; dsum[warp][3] = p4;
        }
        __syncthreads();
        if (tid == 0) {
            for (int k = 0; k < 4; ++k) {
                double v = dsum[0][k] + dsum[1][k] + dsum[2][k] + dsum[3][k];
                __hip_atomic_store(gsum + g * 4 + k, v, __ATOMIC_RELAXED,
                                   __HIP_MEMORY_SCOPE_AGENT);
            }
            asm volatile("s_waitcnt vmcnt(0)" ::: "memory");
            int vg = __hip_atomic_fetch_add(ctr + C_TGLOB, 1,
                                            __ATOMIC_RELAXED, __HIP_MEMORY_SCOPE_AGENT);
            flag = (vg == NGRP - 1);
        }
    }
    __syncthreads();
    if (!flag) return;

    // global finisher: sum 16 partials, solve 2x2, residual over targets
    if (warp == 0) {
        double s1 = 0, s2 = 0, t0 = 0, t1 = 0;
        if (lane < NGRP) {
            s1 = __hip_atomic_load(gsum + lane * 4 + 0, __ATOMIC_RELAXED, __HIP_MEMORY_SCOPE_AGENT);
            s2 = __hip_atomic_load(gsum + lane * 4 + 1, __ATOMIC_RELAXED, __HIP_MEMORY_SCOPE_AGENT);
            t0 = __hip_atomic_load(gsum + lane * 4 + 2, __ATOMIC_RELAXED, __HIP_MEMORY_SCOPE_AGENT);
            t1 = __hip_atomic_load(gsum + lane * 4 + 3, __ATOMIC_RELAXED, __HIP_MEMORY_SCOPE_AGENT);
        }
        for (int o = 32; o; o >>= 1) {
            s1 += __shfl_down(s1, o);
            s2 += __shfl_down(s2, o);
            t0 += __shfl_down(t0, o);
            t1 += __shfl_down(t1, o);
        }
        if (lane == 0) {
            double n = (double)NN;
            double det = n * s2 - s1 * s1;
            wb[0] = (n * t1 - s1 * t0) / det;   // w
            wb[1] = (s2 * t0 - s1 * t1) / det;  // b
        }
    }
    __syncthreads();
    const double w = wb[0];
    const double eb = exp(wb[1]);
    const float wf = (float)w;
    double racc = 0;
    for (int p = tid; p < nl; p += 256) {
        int r = lst[p];
        unsigned long long bits = __hip_atomic_load(ND + r, __ATOMIC_RELAXED,
                                                    __HIP_MEMORY_SCOPE_AGENT);
        float2 nd; __builtin_memcpy(&nd, &bits, 8);
        double Nd = (double)nd.x;
        double Ed = Nd + 0.5 * (double)nd.y;
        double pr = (nd.x > 0.f) ? (double)exp2f(wf * log2f(nd.x)) : 0.0;
        double rv = eb * pr - Ed;
        racc += rv * rv;
    }
    for (int o = 32; o; o >>= 1) racc += __shfl_down(racc, o);
    if (lane == 0) sh[warp] = racc;
    __syncthreads();
    if (tid == 0) out[0] = (float)(sh[0] + sh[1] + sh[2] + sh[3]);
}

extern "C" void kernel_launch(void* const* d_in, const int* in_sizes, int n_in,
                              void* d_out, int out_size, void* d_ws, size_t ws_size,
                              hipStream_t stream) {
    const int*   tri_idx = (const int*)d_in[0];
    const float* tri_w   = (const float*)d_in[1];
    const int*   lst     = (const int*)d_in[2];
    const int m  = in_sizes[1];          // number of edges
    const int nl = in_sizes[2];          // number of targets

    char* base = (char*)d_ws;
    int*      ctr  = (int*)base;
    int*      cnt  = (int*)(base + OFF_CNT);
    unsigned* entp = (unsigned*)(base + OFF_ENTP);
    unsigned long long* ND = (unsigned long long*)(base + OFF_ND);
    double*   gsum = (double*)(base + OFF_GSUM);
    float*    out  = (float*)d_out;

    zeroall_kernel<<<(Z4 + 255) / 256, 256, 0, stream>>>((float4*)base);
    fused_kernel<<<D3B, 256, 0, stream>>>(tri_idx, tri_w, m, lst, nl,
                                          cnt, entp, ND, gsum, ctr, out);
}

// Round 15
// 50.287 us; speedup vs baseline: 3.9197x; 1.0065x over previous
//
#include <hip/hip_runtime.h>
#include <math.h>

#define NN   4096
#define NN4  (NN/4)
#define CAP  128      // slots per row; Poisson(64) -> 128 = 8 sigma, never hit
#define RPB  4        // rows per block in diag3 phase
#define D3B  (NN/RPB) // 1024 blocks
#define NGRP 16       // tail groups (of 64 blocks)
#define GPAD 32       // ints per counter line (128 B)
#define CPAD 32       // ints per scatter counter line (R14: private line/counter)

// counter indices (ints from ctr base) -- only the tail cascade needs counters
#define C_TGRP  0                  // 16 lines
#define C_TGLOB (16 * GPAD)

// ---- workspace layout (bytes from d_ws) ----
// ctr  @ 0       : 17*GPAD i32 (2.2 KB) tail cascade counters
// cnt  @ 6656    : NN*CPAD i32 (512 KB) one counter per 128 B line
// entp @ 530944  : NN*CAP u32 (2 MiB)   packed col<<8|w entries (ZEROED)
// ND   @ 2628096 : NN u64 (32 KB)       packed float2 {N, D3}
// gsum @ 2660864 : NGRP*4 f64 (512 B)
#define OFF_CNT  6656
#define OFF_ENTP 530944
#define OFF_ND   2628096
#define OFF_GSUM 2660864
#define ZBYTES   OFF_ND            // zero ctr+cnt+entp (ND/gsum fully overwritten)
#define Z4       (ZBYTES / 16)

// ---------------- bootstrap: zero ctr + cnt + entp ----------------
// Zero-filled entp is load-bearing (R10): empty slots decode to (col 0, w 0)
// -> contribute exactly 0 -> no masking anywhere downstream.
__global__ __launch_bounds__(256) void zeroall_kernel(float4* __restrict__ z) {
    int t = blockIdx.x * 256 + threadIdx.x;
    if (t < Z4) z[t] = make_float4(0.f, 0.f, 0.f, 0.f);
}

// ---------------- scatter: NORMAL cached stores (R15 change) ----------------
// De-fused => inter-dispatch coherence is free (end-of-kernel L2 writeback +
// next dispatch's invalidate). R14's agent write-through paid a 64 B HBM line
// per 4 B store (WRITE_SIZE 16.5 MB = 262K x 64 B); cached write-back stores
// accumulate in L2 and flush ~2.5 MB of whole lines at the boundary.
// A = scatter + A^T - diag(diag): row s gets (d,w), row d gets (s,w) once.
__global__ void scatter_kernel(const int* __restrict__ idx,
                               const float* __restrict__ wgt,
                               int* __restrict__ cnt,
                               unsigned* __restrict__ entp, int m) {
    int e = blockIdx.x * blockDim.x + threadIdx.x;
    if (e < m) {
        int2 sd = ((const int2*)idx)[e];
        int s = sd.x, d = sd.y;
        unsigned ival = (unsigned)(int)wgt[e];
        if (ival > 255u) ival = 255u;
        int p = atomicAdd(cnt + s * CPAD, 1);     // device RMW, private line
        if (p < CAP) entp[(size_t)s * CAP + p] = ((unsigned)d << 8) | ival;
        if (s != d) {
            int q = atomicAdd(cnt + d * CPAD, 1);
            if (q < CAP) entp[(size_t)d * CAP + q] = ((unsigned)s << 8) | ival;
        }
    }
}

// ---------------- diag(A^3)/rowsum + cascade OLS/residual tail --------------
// diag(A^3)_i = sum_{(j,w) in row i} w * sum_{(k,w') in row j} w' * A_ik;
// A_ik from dense LDS image (LDS atomicAdd merge; exact small-int f32 adds ->
// order-independent -> deterministic). entp/cnt read with normal loads
// (boundary coherence). ND is cross-block WITHIN this kernel -> agent
// write-through + vmcnt drain + hierarchical counters (R5/R8 proven).
__global__ __launch_bounds__(256, 4) void diag3stats_kernel(
        const int* __restrict__ cnt,
        const unsigned* __restrict__ entp,
        unsigned long long* __restrict__ ND,
        const int* __restrict__ lst, int nl,
        int* __restrict__ ctr, double* __restrict__ gsum,
        float* __restrict__ out) {
    __shared__ float    lrow[NN];    // 16 KB dense image of current row
    __shared__ int      lcol[CAP];   // decoded cols of row i (slot-indexed)
    __shared__ float    lval[CAP];   // decoded weights of row i
    __shared__ float    red[8];
    __shared__ int      flag;
    __shared__ double   dsum[4][4];
    __shared__ double   wb[2];
    __shared__ double   sh[4];

    const int tid  = threadIdx.x;
    const int bid  = blockIdx.x;
    const int warp = tid >> 6, lane = tid & 63;

    // ---- P2: 4 rows per block (R13/R14 interior, unchanged) ----
    {
        const int i0 = bid * RPB;
        float4* l4 = (float4*)lrow;

        int mi_arr[RPB];
        #pragma unroll
        for (int r = 0; r < RPB; ++r) {
            int c = cnt[(i0 + r) * CPAD];          // normal load (boundary-fresh)
            mi_arr[r] = c > CAP ? CAP : c;
        }
        unsigned pk = 0u;
        if (tid < CAP) pk = entp[(size_t)i0 * CAP + tid];

        for (int rr = 0; rr < RPB; ++rr) {
            const int i = i0 + rr;
            const int mi = mi_arr[rr];
            for (int k = tid; k < NN4; k += 256) l4[k] = make_float4(0.f, 0.f, 0.f, 0.f);
            __syncthreads();

            float vv = 0.f;
            if (tid < CAP) {
                int col = pk >> 8;
                vv = (float)(pk & 0xffu);
                lcol[tid] = col;
                lval[tid] = vv;
                atomicAdd(&lrow[col], vv);   // branchless: empty slots add 0 to lrow[0]
            }
            float nsum = vv;
            for (int o = 32; o; o >>= 1) nsum += __shfl_down(nsum, o);
            if (lane == 0) red[warp] = nsum;
            __syncthreads();

            unsigned pknext = 0u;
            if (rr + 1 < RPB && tid < CAP) pknext = entp[(size_t)(i + 1) * CAP + tid];
            asm volatile("" : "+v"(pknext));

            // one dwordx2 (whole 512 B neighbor row) per item, 4 in flight/wave
            float acc = 0.f;
            for (int t = warp; t < mi; t += 16) {
                const int t1 = t + 4, t2 = t + 8, t3 = t + 12;
                const bool b1 = t1 < mi, b2 = t2 < mi, b3 = t3 < mi;
                int   c0 = lcol[t];
                int   c1 = b1 ? lcol[t1] : 0;
                int   c2 = b2 ? lcol[t2] : 0;
                int   c3 = b3 ? lcol[t3] : 0;
                float a0 = lval[t];
                float a1 = b1 ? lval[t1] : 0.f;
                float a2 = b2 ? lval[t2] : 0.f;
                float a3 = b3 ? lval[t3] : 0.f;
                uint2 q0 = ((const uint2*)(entp + (size_t)c0 * CAP))[lane];
                uint2 q1 = ((const uint2*)(entp + (size_t)c1 * CAP))[lane];
                uint2 q2 = ((const uint2*)(entp + (size_t)c2 * CAP))[lane];
                uint2 q3 = ((const uint2*)(entp + (size_t)c3 * CAP))[lane];
                float d0 = (float)(q0.x & 0xffu) * lrow[q0.x >> 8]
                         + (float)(q0.y & 0xffu) * lrow[q0.y >> 8];
                float d1 = (float)(q1.x & 0xffu) * lrow[q1.x >> 8]
                         + (float)(q1.y & 0xffu) * lrow[q1.y >> 8];
                float d2 = (float)(q2.x & 0xffu) * lrow[q2.x >> 8]
                         + (float)(q2.y & 0xffu) * lrow[q2.y >> 8];
                float d3 = (float)(q3.x & 0xffu) * lrow[q3.x >> 8]
                         + (float)(q3.y & 0xffu) * lrow[q3.y >> 8];
                acc += a0 * d0 + a1 * d1 + a2 * d2 + a3 * d3;
            }
            for (int o = 32; o; o >>= 1) acc += __shfl_down(acc, o);
            if (lane == 0) red[4 + warp] = acc;
            __syncthreads();

            if (tid == 0) {
                float2 nd = make_float2(red[0] + red[1] + red[2] + red[3],
                                        red[4] + red[5] + red[6] + red[7]);
                unsigned long long bits;
                __builtin_memcpy(&bits, &nd, 8);
                __hip_atomic_store(ND + i, bits, __ATOMIC_RELAXED, __HIP_MEMORY_SCOPE_AGENT);
            }
            pk = pknext;
            __syncthreads();   // lrow reads done before next row's zeroing
        }
    }

    // ---- cascade tail (non-blocking; only finishers continue) --------------
    if (tid == 0) {
        asm volatile("s_waitcnt vmcnt(0)" ::: "memory");  // drain 4 ND stores
        int v = __hip_atomic_fetch_add(ctr + C_TGRP + (bid >> 6) * GPAD, 1,
                                       __ATOMIC_RELAXED, __HIP_MEMORY_SCOPE_AGENT);
        flag = (v == 63);
    }
    __syncthreads();
    if (!flag) return;

    // group finisher: 256 threads, one row each -> fp64 OLS partials
    const int g = bid >> 6;
    {
        int r = g * 256 + tid;
        unsigned long long bits = __hip_atomic_load(ND + r, __ATOMIC_RELAXED,
                                                    __HIP_MEMORY_SCOPE_AGENT);
        float2 nd; __builtin_memcpy(&nd, &bits, 8);
        double Nd = (double)nd.x;
        double Ed = Nd + 0.5 * (double)nd.y;
        double ln = (double)logf((float)(Nd + 1e-20));
        double le = (double)logf((float)(Ed + 1e-20));
        double p1 = ln, p2 = ln * ln, p3 = le, p4 = ln * le;
        for (int o = 32; o; o >>= 1) {
            p1 += __shfl_down(p1, o);
            p2 += __shfl_down(p2, o);
            p3 += __shfl_down(p3, o);
            p4 += __shfl_down(p4, o);
        }
        if (lane == 0) {
            dsum[warp][0] = p1; dsum[warp][1] = p2;
            dsum[warp][2] = p3; dsum[warp][3] = p4;
        }
        __syncthreads();
        if (tid == 0) {
            for (int k = 0; k < 4; ++k) {
                double v = dsum[0][k] + dsum[1][k] + dsum[2][k] + dsum[3][k];
                __hip_atomic_store(gsum + g * 4 + k, v, __ATOMIC_RELAXED,
                                   __HIP_MEMORY_SCOPE_AGENT);
            }
            asm volatile("s_waitcnt vmcnt(0)" ::: "memory");
            int vg = __hip_atomic_fetch_add(ctr + C_TGLOB, 1,
                                            __ATOMIC_RELAXED, __HIP_MEMORY_SCOPE_AGENT);
            flag = (vg == NGRP - 1);
        }
    }
    __syncthreads();
    if (!flag) return;

    // global finisher: sum 16 partials, solve 2x2, residual over targets
    if (warp == 0) {
        double s1 = 0, s2 = 0, t0 = 0, t1 = 0;
        if (lane < NGRP) {
            s1 = __hip_atomic_load(gsum + lane * 4 + 0, __ATOMIC_RELAXED, __HIP_MEMORY_SCOPE_AGENT);
            s2 = __hip_atomic_load(gsum + lane * 4 + 1, __ATOMIC_RELAXED, __HIP_MEMORY_SCOPE_AGENT);
            t0 = __hip_atomic_load(gsum + lane * 4 + 2, __ATOMIC_RELAXED, __HIP_MEMORY_SCOPE_AGENT);
            t1 = __hip_atomic_load(gsum + lane * 4 + 3, __ATOMIC_RELAXED, __HIP_MEMORY_SCOPE_AGENT);
        }
        for (int o = 32; o; o >>= 1) {
            s1 += __shfl_down(s1, o);
            s2 += __shfl_down(s2, o);
            t0 += __shfl_down(t0, o);
            t1 += __shfl_down(t1, o);
        }
        if (lane == 0) {
            double n = (double)NN;
            double det = n * s2 - s1 * s1;
            wb[0] = (n * t1 - s1 * t0) / det;   // w
            wb[1] = (s2 * t0 - s1 * t1) / det;  // b
        }
    }
    __syncthreads();
    const double w = wb[0];
    const double eb = exp(wb[1]);
    const float wf = (float)w;
    double racc = 0;
    for (int p = tid; p < nl; p += 256) {
        int r = lst[p];
        unsigned long long bits = __hip_atomic_load(ND + r, __ATOMIC_RELAXED,
                                                    __HIP_MEMORY_SCOPE_AGENT);
        float2 nd; __builtin_memcpy(&nd, &bits, 8);
        double Nd = (double)nd.x;
        double Ed = Nd + 0.5 * (double)nd.y;
        double pr = (nd.x > 0.f) ? (double)exp2f(wf * log2f(nd.x)) : 0.0;
        double rv = eb * pr - Ed;
        racc += rv * rv;
    }
    for (int o = 32; o; o >>= 1) racc += __shfl_down(racc, o);
    if (lane == 0) sh[warp] = racc;
    __syncthreads();
    if (tid == 0) out[0] = (float)(sh[0] + sh[1] + sh[2] + sh[3]);
}

extern "C" void kernel_launch(void* const* d_in, const int* in_sizes, int n_in,
                              void* d_out, int out_size, void* d_ws, size_t ws_size,
                              hipStream_t stream) {
    const int*   tri_idx = (const int*)d_in[0];
    const float* tri_w   = (const float*)d_in[1];
    const int*   lst     = (const int*)d_in[2];
    const int m  = in_sizes[1];          // number of edges
    const int nl = in_sizes[2];          // number of targets

    char* base = (char*)d_ws;
    int*      ctr  = (int*)base;
    int*      cnt  = (int*)(base + OFF_CNT);
    unsigned* entp = (unsigned*)(base + OFF_ENTP);
    unsigned long long* ND = (unsigned long long*)(base + OFF_ND);
    double*   gsum = (double*)(base + OFF_GSUM);
    float*    out  = (float*)d_out;

    zeroall_kernel<<<(Z4 + 255) / 256, 256, 0, stream>>>((float4*)base);
    scatter_kernel<<<(m + 255) / 256, 256, 0, stream>>>(tri_idx, tri_w, cnt, entp, m);
    diag3stats_kernel<<<D3B, 256, 0, stream>>>(cnt, entp, ND, lst, nl, ctr, gsum, out);
}